// Round 8
// baseline (1339.971 us; speedup 1.0000x reference)
//
#include <hip/hip_runtime.h>

#define NNODES 50000
#define HID 128
#define NREL 9
#define NLAYERS 3
#define NEDGES 600000
#define NRANGE 8
#define RSPAN (NNODES / NRANGE)          // 6250

// bin = (d*8 + src/RSPAN)*9 + rel   (dest-major, then src-range, then rel)
#define NBINS2 (NNODES * NRANGE * NREL)  // 3,600,000
#define SCAN_CHUNK 8192
#define NBLK ((NBINS2 + SCAN_CHUNK - 1) / SCAN_CHUNK)   // 440

#define KTOT (NREL * HID)                // 1152
#define GM 16                            // rows per fused block -> 3125 blocks (exact)
#define PITCHF 1154                      // f32 panel pitch (1154 % 32 == 2 -> balanced b128 banks)
#define FPITCH 136                       // epilogue bf16 Et pitch (reuses panel memory)

// prep_kernel block ranges
#define HIST_BLKS ((NEDGES + 255) / 256)            // 2344
#define EMB_BLKS  ((NNODES * HID / 8) / 256)        // 3125
#define W_BLKS    (NLAYERS * NREL)                  // 27

typedef __attribute__((ext_vector_type(8))) short short8;
typedef __attribute__((ext_vector_type(4))) float f32x4;

__device__ __forceinline__ short f2bf(float f) {
    union { float f; unsigned u; } c; c.f = f;
    unsigned r = c.u + 0x7fff + ((c.u >> 16) & 1);   // RNE
    return (short)(r >> 16);
}
__device__ __forceinline__ float bf2f(short v) {
    return __uint_as_float(((unsigned)(unsigned short)v) << 16);
}

// ---------------- prep: histogram + emb convert + W convert (one dispatch) ----------------
// Wt2[l][n][r*128+kk] = bf16(W[l][r][kk][n])   (r-major K)

__global__ __launch_bounds__(256) void prep_kernel(const int* __restrict__ dst,
                                                   const int* __restrict__ src,
                                                   const int* __restrict__ etype,
                                                   int* __restrict__ bins,
                                                   const float* __restrict__ E,
                                                   short* __restrict__ Ebf,
                                                   const float* __restrict__ W,
                                                   short* __restrict__ Wt2) {
    int b = blockIdx.x, tid = threadIdx.x;
    if (b < HIST_BLKS) {
        int e = b * 256 + tid;
        if (e < NEDGES) {
            int bin = (dst[e] * NRANGE + src[e] / RSPAN) * NREL + etype[e];
            atomicAdd(&bins[bin], 1);
        }
    } else if (b < HIST_BLKS + EMB_BLKS) {
        int gid = (b - HIST_BLKS) * 256 + tid;
        const float* p = E + (size_t)gid * 8;
        float4 v0 = *(const float4*)p;
        float4 v1 = *(const float4*)(p + 4);
        short8 o = {f2bf(v0.x), f2bf(v0.y), f2bf(v0.z), f2bf(v0.w),
                    f2bf(v1.x), f2bf(v1.y), f2bf(v1.z), f2bf(v1.w)};
        *(short8*)(Ebf + (size_t)gid * 8) = o;
    } else {
        int lr = b - HIST_BLKS - EMB_BLKS;
        int l = lr / NREL, r = lr - l * NREL;
        const float* w = W + (size_t)lr * HID * HID;
        short* o = Wt2 + (size_t)l * HID * KTOT;
#pragma unroll 4
        for (int i = 0; i < 64; i++) {
            int elem = i * 256 + tid;
            int kk = elem >> 7, n = elem & 127;
            o[(size_t)n * KTOT + r * HID + kk] = f2bf(w[elem]);
        }
    }
}

// ---------------- scans over 3.6M bins (8192-bin chunks, 32 bins/thread) ----------------

__global__ __launch_bounds__(256) void scan_pass1(const int* __restrict__ bins,
                                                  int* __restrict__ blocksum) {
    __shared__ int red[256];
    int b = blockIdx.x, t = threadIdx.x;
    int i0 = b * SCAN_CHUNK + t * 32;
    int s = 0;
    for (int k = 0; k < 32; k++)
        if (i0 + k < NBINS2) s += bins[i0 + k];
    red[t] = s;
    __syncthreads();
    for (int off = 128; off > 0; off >>= 1) {
        if (t < off) red[t] += red[t + off];
        __syncthreads();
    }
    if (t == 0) blocksum[b] = red[0];
}

__global__ __launch_bounds__(512) void scan_pass2(const int* __restrict__ blocksum,
                                                  int* __restrict__ blockoff,
                                                  int* __restrict__ rowptr) {
    __shared__ int s[512];
    int t = threadIdx.x;
    int v = (t < NBLK) ? blocksum[t] : 0;
    s[t] = v;
    __syncthreads();
    for (int off = 1; off < 512; off <<= 1) {
        int x = (t >= off) ? s[t - off] : 0;
        __syncthreads();
        s[t] += x;
        __syncthreads();
    }
    if (t < NBLK) blockoff[t] = s[t] - v;
    if (t == 0) rowptr[NBINS2] = NEDGES;
}

__global__ __launch_bounds__(256) void scan_pass3(const int* __restrict__ bins,
                                                  const int* __restrict__ blockoff,
                                                  int* __restrict__ rowptr,
                                                  int* __restrict__ cursor) {
    __shared__ int sc[256];
    int b = blockIdx.x, t = threadIdx.x;
    int i0 = b * SCAN_CHUNK + t * 32;
    int s = 0;
    for (int k = 0; k < 32; k++)
        if (i0 + k < NBINS2) s += bins[i0 + k];
    sc[t] = s;
    __syncthreads();
    for (int off = 1; off < 256; off <<= 1) {
        int x = (t >= off) ? sc[t - off] : 0;
        __syncthreads();
        sc[t] += x;
        __syncthreads();
    }
    int run = blockoff[b] + (sc[t] - s);
    for (int k = 0; k < 32; k++) {              // re-read bins (L2-hot) to avoid 32-reg arrays
        if (i0 + k < NBINS2) {
            rowptr[i0 + k] = run;
            cursor[i0 + k] = run;
            run += bins[i0 + k];
        }
    }
}

__global__ void place_kernel(const int* __restrict__ dst, const int* __restrict__ src,
                             const int* __restrict__ etype,
                             int* __restrict__ cursor, int* __restrict__ bsrc) {
    int e = blockIdx.x * blockDim.x + threadIdx.x;
    if (e < 8) bsrc[NEDGES + e] = 0;     // zero lookahead pad
    if (e < NEDGES) {
        int s = src[e];
        int bin = (dst[e] * NRANGE + s / RSPAN) * NREL + etype[e];
        int pos = atomicAdd(&cursor[bin], 1);
        bsrc[pos] = s;
    }
}

// ---------------- fused layer: phase-local gather + full-K MFMA sweep ----------------
// Per block: 16 dest rows, 3125 blocks, 2 blocks/CU (79 KB LDS). Gather walks the
// 8 src-range PHASES in rotated order (start = bid&7): all blocks on one XCD work
// the same 1.6 MB slice of H at a time -> XCD-L2-resident random reads. Per
// (phase, rel) sub-bin: round-5's proven 4-wide masked edge group into registers,
// then ONE read-add-write flush into a single-owner f32 LDS panel (no atomics;
// thread (row, colgroup) exclusively owns its 8-f32 slice). Empty sub-bins skip.
// Then 1 barrier -> 36-chunk MFMA (A = f32 panel cvt'd at frag load, B from L2)
// -> verified epilogue (counts = sum of per-phase bin sizes).
// C mapping (verified): row = lq*4 + reg, col = n0 + nt*16 + lm.

__global__ __launch_bounds__(256, 2) void fused_kernel(const short* __restrict__ Hin,
                                                       const short* __restrict__ Wt2l,
                                                       const float* __restrict__ Bias, // [9][128]
                                                       const int* __restrict__ rowptr,
                                                       const int* __restrict__ bsrc,
                                                       short* __restrict__ HoutBf,     // !last
                                                       float* __restrict__ HoutF,      // last
                                                       int last) {
    __shared__ float PF[GM * PITCHF];             // 73,856 B f32 panel; reused as Et
    __shared__ int   rp_s[GM * NRANGE * NREL + 1]; // 1153 ints
    __shared__ float cnt_s[GM][NREL];             // 576 B

    int tid  = threadIdx.x;
    int wave = tid >> 6, lane = tid & 63;
    int lm = lane & 15, lq = lane >> 4;
    int row0 = blockIdx.x * GM;
    int n0   = wave * 32;
    int grow = tid >> 4;          // 0..15 dest row
    int cg   = tid & 15;          // col group (8 cols; 16 B bf16 load / 32 B f32 slice)

    // stage the block's contiguous 1153 rowptr boundaries
    for (int i = tid; i < GM * NRANGE * NREL + 1; i += 256)
        rp_s[i] = rowptr[row0 * (NRANGE * NREL) + i];

    // zero own panel region (single owner -> no sync needed before gather)
    float* prow = &PF[grow * PITCHF];
    {
        float4 z = {0.f, 0.f, 0.f, 0.f};
#pragma unroll
        for (int r = 0; r < NREL; r++) {
            *(float4*)(prow + r * HID + cg * 8)     = z;
            *(float4*)(prow + r * HID + cg * 8 + 4) = z;
        }
    }
    __syncthreads();   // rp_s visible

    // per-(row, rel) counts = sum of per-phase bin sizes (for the bias epilogue)
    if (tid < GM * NREL) {
        int row = tid / NREL, rr = tid - (tid / NREL) * NREL;
        int c = 0;
#pragma unroll
        for (int p = 0; p < NRANGE; p++) {
            int bidx = row * (NRANGE * NREL) + p * NREL + rr;
            c += rp_s[bidx + 1] - rp_s[bidx];
        }
        cnt_s[row][rr] = (float)c;
    }

    // ---- gather: phase-rotated walk, register acc per sub-bin, f32 LDS RMW flush ----
    const short* hb = Hin + cg * 8;
    int ph0 = blockIdx.x & 7;     // XCD phase alignment (bid%8 -> XCD)

    for (int pp = 0; pp < NRANGE; pp++) {
        int p = (pp + ph0) & 7;
        int base = grow * (NRANGE * NREL) + p * NREL;
        if (rp_s[base] == rp_s[base + NREL]) continue;      // empty phase for this row
#pragma unroll 1
        for (int r = 0; r < NREL; r++) {
            int rs = rp_s[base + r];
            int re = rp_s[base + r + 1];
            if (rs == re) continue;                          // empty sub-bin
            float ga[8];
#pragma unroll
            for (int k = 0; k < 8; k++) ga[k] = 0.f;
            for (int j = rs; j < re; j += 4) {               // round-5 4-wide masked group
                int rem = re - j;
                int s0 = bsrc[j];
                int t1 = bsrc[j + 1];
                int t2 = bsrc[j + 2];
                int t3 = bsrc[j + 3];
                int s1 = (rem > 1) ? t1 : s0;
                int s2 = (rem > 2) ? t2 : s0;
                int s3 = (rem > 3) ? t3 : s0;
                short8 a = *(const short8*)(hb + (size_t)s0 * HID);
                short8 b = *(const short8*)(hb + (size_t)s1 * HID);
                short8 c = *(const short8*)(hb + (size_t)s2 * HID);
                short8 d = *(const short8*)(hb + (size_t)s3 * HID);
                float m1 = (rem > 1) ? 1.f : 0.f;
                float m2 = (rem > 2) ? 1.f : 0.f;
                float m3 = (rem > 3) ? 1.f : 0.f;
#pragma unroll
                for (int k = 0; k < 8; k++)
                    ga[k] += (bf2f(a[k]) + m1 * bf2f(b[k])) + (m2 * bf2f(c[k]) + m3 * bf2f(d[k]));
            }
            // flush: single-owner read-add-write into panel slice r
            float* dp = prow + r * HID + cg * 8;
            float4 x0 = *(float4*)dp;
            float4 x1 = *(float4*)(dp + 4);
            x0.x += ga[0]; x0.y += ga[1]; x0.z += ga[2]; x0.w += ga[3];
            x1.x += ga[4]; x1.y += ga[5]; x1.z += ga[6]; x1.w += ga[7];
            *(float4*)dp       = x0;
            *(float4*)(dp + 4) = x1;
        }
    }
    __syncthreads();   // panel complete

    // ---- MFMA sweep: A from f32 panel (cvt at frag load), B streamed from L2 ----
    f32x4 acc[2];
    acc[0] = (f32x4){0.f, 0.f, 0.f, 0.f};
    acc[1] = (f32x4){0.f, 0.f, 0.f, 0.f};

    const short* wb0 = Wt2l + (size_t)(n0 + lm) * KTOT + lq * 8;
    const short* wb1 = wb0 + (size_t)16 * KTOT;
    const float* pf  = &PF[lm * PITCHF];

#pragma unroll 4
    for (int kc = 0; kc < KTOT / 32; kc++) {      // 36 chunks
        short8 b0 = *(const short8*)(wb0 + kc * 32);
        short8 b1 = *(const short8*)(wb1 + kc * 32);
        const float4* pa = (const float4*)(pf + kc * 32 + lq * 8);
        float4 x0 = pa[0], x1 = pa[1];
        short8 af = {f2bf(x0.x), f2bf(x0.y), f2bf(x0.z), f2bf(x0.w),
                     f2bf(x1.x), f2bf(x1.y), f2bf(x1.z), f2bf(x1.w)};
        __builtin_amdgcn_s_setprio(1);
        acc[0] = __builtin_amdgcn_mfma_f32_16x16x32_bf16(af, b0, acc[0], 0, 0, 0);
        acc[1] = __builtin_amdgcn_mfma_f32_16x16x32_bf16(af, b1, acc[1], 0, 0, 0);
        __builtin_amdgcn_s_setprio(0);
    }
    __syncthreads();   // panel reads done; safe to reuse as Et

    // ---- epilogue: counts-weighted bias (global, L2-hot), activation, store ----
    if (!last) {
        short (*Et)[FPITCH] = (short(*)[FPITCH])&PF[0];
#pragma unroll
        for (int reg = 0; reg < 4; reg++) {
            int rl = lq * 4 + reg;
#pragma unroll
            for (int nt = 0; nt < 2; nt++) {
                int n = n0 + nt * 16 + lm;
                float b = 0.f;
#pragma unroll
                for (int rr = 0; rr < NREL; rr++) b += cnt_s[rl][rr] * Bias[rr * HID + n];
                float o = fmaxf(acc[nt][reg] + b, 0.f);
                Et[rl][n] = f2bf(o);
            }
        }
        __syncthreads();
        {
            int row = tid >> 4, cc = tid & 15;
            int d = row0 + row;
            *(short8*)(HoutBf + (size_t)d * HID + cc * 8) = *(const short8*)&Et[row][cc * 8];
        }
    } else {
#pragma unroll
        for (int reg = 0; reg < 4; reg++) {
            int rl = lq * 4 + reg;
            int d  = row0 + rl;
#pragma unroll
            for (int nt = 0; nt < 2; nt++) {
                int n = n0 + nt * 16 + lm;
                float b = 0.f;
#pragma unroll
                for (int rr = 0; rr < NREL; rr++) b += cnt_s[rl][rr] * Bias[rr * HID + n];
                HoutF[(size_t)d * HID + n] = acc[nt][reg] + b;
            }
        }
    }
}

// ---------------- driver ----------------

extern "C" void kernel_launch(void* const* d_in, const int* in_sizes, int n_in,
                              void* d_out, int out_size, void* d_ws, size_t ws_size,
                              hipStream_t stream) {
    const int*   edge_index = (const int*)d_in[0];   // [2, NEDGES]: row0=dest, row1=src
    const int*   etype      = (const int*)d_in[1];
    const float* emb        = (const float*)d_in[2];
    const float* W          = (const float*)d_in[3]; // [3,9,128,128]
    const float* Bias       = (const float*)d_in[4]; // [3,9,128]
    float*       out        = (float*)d_out;

    const int* dst  = edge_index;
    const int* srcA = edge_index + NEDGES;

    // ws layout (no S; H double-buffered; 3.6M-bin CSR arrays ~43 MB)
    short* Ebf  = (short*)d_ws;                             // 50000*128 bf16
    short* HbfA = Ebf  + (size_t)NNODES * HID;              // 50000*128 bf16
    short* HbfB = HbfA + (size_t)NNODES * HID;              // 50000*128 bf16
    short* Wt2  = HbfB + (size_t)NNODES * HID;              // 3*128*1152 bf16
    int*   bsrc     = (int*)(Wt2 + (size_t)NLAYERS * HID * KTOT);  // NEDGES + 8 pad
    int*   bins     = bsrc + NEDGES + 8;
    int*   cursor   = bins + NBINS2;
    int*   rowptr   = cursor + NBINS2;                      // NBINS2+1
    int*   blocksum = rowptr + NBINS2 + 1;
    int*   blockoff = blocksum + NBLK;

    hipMemsetAsync(bins, 0, NBINS2 * sizeof(int), stream);
    prep_kernel<<<HIST_BLKS + EMB_BLKS + W_BLKS, 256, 0, stream>>>(
        dst, srcA, etype, bins, emb, Ebf, W, Wt2);
    scan_pass1<<<NBLK, 256, 0, stream>>>(bins, blocksum);
    scan_pass2<<<1, 512, 0, stream>>>(blocksum, blockoff, rowptr);
    scan_pass3<<<NBLK, 256, 0, stream>>>(bins, blockoff, rowptr, cursor);
    place_kernel<<<(NEDGES + 255) / 256, 256, 0, stream>>>(dst, srcA, etype, cursor, bsrc);

    const int nblocks = NNODES / GM;   // 3125 (exact)
    const short* Hin = Ebf;
    for (int l = 0; l < NLAYERS; l++) {
        int last = (l + 1 == NLAYERS);
        short* Hout = (l == 0) ? HbfA : HbfB;       // alternate; never in-place
        if (l == 2) Hout = HbfA;                    // unused on last layer
        const short* Wtl = Wt2 + (size_t)l * HID * KTOT;
        const float* Bl  = Bias + (size_t)l * NREL * HID;
        fused_kernel<<<nblocks, 256, 0, stream>>>(
            Hin, Wtl, Bl, rowptr, bsrc, Hout, out, last);
        Hin = Hout;
    }
}

// Round 9
// 909.983 us; speedup vs baseline: 1.4725x; 1.4725x over previous
//
#include <hip/hip_runtime.h>

#define NNODES 50000
#define HID 128
#define NREL 9
#define NLAYERS 3
#define NEDGES 600000

#define NBINS (NREL * NNODES)          // 450000, bin = r*NNODES + d  (r-major)
#define SCAN_CHUNK 1024
#define NBLK ((NBINS + SCAN_CHUNK - 1) / SCAN_CHUNK)   // 440

#define KTOT (NREL * HID)               // 1152
#define GM 16                           // fused M-tile -> 3125 blocks (50000/16 exact)
#define FPITCH 136                      // panel/Et pitch in shorts (272 B rows, 2-way banks = free)

// prep_kernel block ranges
#define HIST_BLKS ((NEDGES + 255) / 256)            // 2344
#define EMB_BLKS  ((NNODES * HID / 8) / 256)        // 3125
#define W_BLKS    (NLAYERS * NREL)                  // 27

typedef __attribute__((ext_vector_type(8))) short short8;
typedef __attribute__((ext_vector_type(4))) float f32x4;

__device__ __forceinline__ short f2bf(float f) {
    union { float f; unsigned u; } c; c.f = f;
    unsigned r = c.u + 0x7fff + ((c.u >> 16) & 1);   // RNE
    return (short)(r >> 16);
}
__device__ __forceinline__ float bf2f(short v) {
    return __uint_as_float(((unsigned)(unsigned short)v) << 16);
}

// ---------------- prep: histogram + emb convert + W convert (one dispatch) ----------------
// Wt2[l][n][r*128+kk] = bf16(W[l][r][kk][n])   (r-major K)

__global__ __launch_bounds__(256) void prep_kernel(const int* __restrict__ dst,
                                                   const int* __restrict__ etype,
                                                   int* __restrict__ bins,
                                                   const float* __restrict__ E,
                                                   short* __restrict__ Ebf,
                                                   const float* __restrict__ W,
                                                   short* __restrict__ Wt2) {
    int b = blockIdx.x, tid = threadIdx.x;
    if (b < HIST_BLKS) {
        int e = b * 256 + tid;
        if (e < NEDGES) {
            int bin = etype[e] * NNODES + dst[e];
            atomicAdd(&bins[bin], 1);
        }
    } else if (b < HIST_BLKS + EMB_BLKS) {
        int gid = (b - HIST_BLKS) * 256 + tid;
        const float* p = E + (size_t)gid * 8;
        float4 v0 = *(const float4*)p;
        float4 v1 = *(const float4*)(p + 4);
        short8 o = {f2bf(v0.x), f2bf(v0.y), f2bf(v0.z), f2bf(v0.w),
                    f2bf(v1.x), f2bf(v1.y), f2bf(v1.z), f2bf(v1.w)};
        *(short8*)(Ebf + (size_t)gid * 8) = o;
    } else {
        int lr = b - HIST_BLKS - EMB_BLKS;
        int l = lr / NREL, r = lr - l * NREL;
        const float* w = W + (size_t)lr * HID * HID;
        short* o = Wt2 + (size_t)l * HID * KTOT;
#pragma unroll 4
        for (int i = 0; i < 64; i++) {
            int elem = i * 256 + tid;
            int kk = elem >> 7, n = elem & 127;
            o[(size_t)n * KTOT + r * HID + kk] = f2bf(w[elem]);
        }
    }
}

// ---------------- scans ----------------

__global__ __launch_bounds__(256) void scan_pass1(const int* __restrict__ bins,
                                                  int* __restrict__ blocksum) {
    __shared__ int red[256];
    int b = blockIdx.x, t = threadIdx.x;
    int i0 = b * SCAN_CHUNK + t * 4;
    int s = 0;
#pragma unroll
    for (int k = 0; k < 4; k++)
        if (i0 + k < NBINS) s += bins[i0 + k];
    red[t] = s;
    __syncthreads();
    for (int off = 128; off > 0; off >>= 1) {
        if (t < off) red[t] += red[t + off];
        __syncthreads();
    }
    if (t == 0) blocksum[b] = red[0];
}

__global__ __launch_bounds__(512) void scan_pass2(const int* __restrict__ blocksum,
                                                  int* __restrict__ blockoff,
                                                  int* __restrict__ rowptr) {
    __shared__ int s[512];
    int t = threadIdx.x;
    int v = (t < NBLK) ? blocksum[t] : 0;
    s[t] = v;
    __syncthreads();
    for (int off = 1; off < 512; off <<= 1) {
        int x = (t >= off) ? s[t - off] : 0;
        __syncthreads();
        s[t] += x;
        __syncthreads();
    }
    if (t < NBLK) blockoff[t] = s[t] - v;
    if (t == 0) rowptr[NBINS] = NEDGES;
}

__global__ __launch_bounds__(256) void scan_pass3(const int* __restrict__ bins,
                                                  const int* __restrict__ blockoff,
                                                  int* __restrict__ rowptr,
                                                  int* __restrict__ cursor) {
    __shared__ int sc[256];
    int b = blockIdx.x, t = threadIdx.x;
    int i0 = b * SCAN_CHUNK + t * 4;
    int v[4], p[4];
    int s = 0;
#pragma unroll
    for (int k = 0; k < 4; k++) {
        v[k] = (i0 + k < NBINS) ? bins[i0 + k] : 0;
        p[k] = s;
        s += v[k];
    }
    sc[t] = s;
    __syncthreads();
    for (int off = 1; off < 256; off <<= 1) {
        int x = (t >= off) ? sc[t - off] : 0;
        __syncthreads();
        sc[t] += x;
        __syncthreads();
    }
    int base = blockoff[b] + (sc[t] - s);
#pragma unroll
    for (int k = 0; k < 4; k++) {
        if (i0 + k < NBINS) {
            rowptr[i0 + k] = base + p[k];
            cursor[i0 + k] = base + p[k];
        }
    }
}

__global__ void place_kernel(const int* __restrict__ dst, const int* __restrict__ src,
                             const int* __restrict__ etype,
                             int* __restrict__ cursor, int* __restrict__ bsrc) {
    int e = blockIdx.x * blockDim.x + threadIdx.x;
    if (e < 8) bsrc[NEDGES + e] = 0;     // zero the lookahead pad
    if (e < NEDGES) {
        int bin = etype[e] * NNODES + dst[e];
        int pos = atomicAdd(&cursor[bin], 1);
        bsrc[pos] = src[e];
    }
}

// ---------------- fused layer: gather (4-wide edge groups) + GEMM + bias + act ----------------
// Round-5 skeleton at GM=16 for occupancy: 3125 blocks, ~13.9 KB LDS, VGPR<=64
// (launch_bounds 256,8) -> up to 8 blocks/CU (32 waves) resident vs round-5's ~2.5.
// Per block: 16 dest rows, dbuf bf16 panel, ONE barrier/relation.
// Gather: 16 lanes/row x 8 cols (16 B/lane); per bin 4 idx loads -> 4 H-slice loads
// ALL in flight -> masked accumulate; next relation's first 4 indices prefetched
// before the barrier. Index loads pad-safe (bsrc +8 pad, zeroed); masked lanes
// multiply valid finite H data by 0.
// Wave shape 16Mx32N; C mapping (verified): row = lq*4+reg, col = n0+nt*16+lm.

__global__ __launch_bounds__(256, 8) void fused_kernel(const short* __restrict__ Hin,
                                                       const short* __restrict__ Wt2l,
                                                       const float* __restrict__ Bias, // [9][128]
                                                       const int* __restrict__ rowptr,
                                                       const int* __restrict__ bsrc,
                                                       short* __restrict__ HoutBf,     // !last
                                                       float* __restrict__ HoutF,      // last
                                                       int last) {
    __shared__ short As[2][GM * FPITCH];          // 2 x 4352 B, [0] reused as Et
    __shared__ int   rp_s[NREL * (GM + 1)];       // 153 ints
    __shared__ float bias_s[NREL * HID];          // 4608 B

    int tid  = threadIdx.x;
    int wave = tid >> 6, lane = tid & 63;
    int lm = lane & 15, lq = lane >> 4;
    int row0 = blockIdx.x * GM;
    int n0   = wave * 32;                 // wave's N base
    int grow = tid >> 4;                  // 0..15 dest row (16 lanes/row)
    int gcc  = tid & 15;                  // 8-col group (16 B/lane)

    // ---- prologue: prefetch rel-0 first 4 indices (pad-safe raw loads) ----
    int rs0 = rowptr[row0 + grow];
    int re0 = rowptr[row0 + grow + 1];
    int pf0 = 0, pf1 = 0, pf2 = 0, pf3 = 0;
    if (rs0 < re0) {
        pf0 = bsrc[rs0];
        pf1 = bsrc[rs0 + 1];
        pf2 = bsrc[rs0 + 2];
        pf3 = bsrc[rs0 + 3];
    }

    // stage rowptr spans (9 x 17; indices r*NNODES + row0 + o are always valid:
    // o=16 lands on the next row/relation boundary, o=16 at r=8,row0=49984 -> NBINS)
    for (int i = tid; i < NREL * (GM + 1); i += 256) {
        int r = i / (GM + 1), o = i - r * (GM + 1);
        rp_s[i] = rowptr[r * NNODES + row0 + o];
    }
    for (int i = tid; i < NREL * HID; i += 256) bias_s[i] = Bias[i];

    f32x4 acc[2];
    acc[0] = (f32x4){0.f, 0.f, 0.f, 0.f};
    acc[1] = (f32x4){0.f, 0.f, 0.f, 0.f};

    __syncthreads();

    const short* wb = Wt2l + (size_t)(n0 + lm) * KTOT + lq * 8;
    const short* hb = Hin + gcc * 8;

    for (int r = 0; r < NREL; r++) {
        short* Ap = &As[r & 1][0];

        // ---- B prefetch: 8 independent 16B loads, consumed after the barrier ----
        short8 bfr[2][4];
#pragma unroll
        for (int nt = 0; nt < 2; nt++)
#pragma unroll
            for (int ks = 0; ks < 4; ks++)
                bfr[nt][ks] = *(const short8*)(wb + (size_t)nt * 16 * KTOT + r * HID + ks * 32);

        // ---- gather: 4-wide edge groups, register accumulation ----
        int rs = rp_s[r * (GM + 1) + grow];
        int re = rp_s[r * (GM + 1) + grow + 1];
        float ga[8];
#pragma unroll
        for (int i = 0; i < 8; i++) ga[i] = 0.f;

        int j = rs;
        if (j < re) {
            // first group: indices already prefetched
            int rem = re - j;
            int s0 = pf0;
            int s1 = (rem > 1) ? pf1 : s0;
            int s2 = (rem > 2) ? pf2 : s0;
            int s3 = (rem > 3) ? pf3 : s0;
            short8 a = *(const short8*)(hb + (size_t)s0 * HID);
            short8 b = *(const short8*)(hb + (size_t)s1 * HID);
            short8 c = *(const short8*)(hb + (size_t)s2 * HID);
            short8 d = *(const short8*)(hb + (size_t)s3 * HID);
            float m1 = (rem > 1) ? 1.f : 0.f;
            float m2 = (rem > 2) ? 1.f : 0.f;
            float m3 = (rem > 3) ? 1.f : 0.f;
#pragma unroll
            for (int k = 0; k < 8; k++)
                ga[k] += (bf2f(a[k]) + m1 * bf2f(b[k])) + (m2 * bf2f(c[k]) + m3 * bf2f(d[k]));
            j += 4;
        }
        for (; j < re; j += 4) {
            // rare long-bin path (>4 edges): pad-safe idx loads, clamped values
            int rem = re - j;
            int s0 = bsrc[j];
            int t1 = bsrc[j + 1];
            int t2 = bsrc[j + 2];
            int t3 = bsrc[j + 3];
            int s1 = (rem > 1) ? t1 : s0;
            int s2 = (rem > 2) ? t2 : s0;
            int s3 = (rem > 3) ? t3 : s0;
            short8 a = *(const short8*)(hb + (size_t)s0 * HID);
            short8 b = *(const short8*)(hb + (size_t)s1 * HID);
            short8 c = *(const short8*)(hb + (size_t)s2 * HID);
            short8 d = *(const short8*)(hb + (size_t)s3 * HID);
            float m1 = (rem > 1) ? 1.f : 0.f;
            float m2 = (rem > 2) ? 1.f : 0.f;
            float m3 = (rem > 3) ? 1.f : 0.f;
#pragma unroll
            for (int k = 0; k < 8; k++)
                ga[k] += (bf2f(a[k]) + m1 * bf2f(b[k])) + (m2 * bf2f(c[k]) + m3 * bf2f(d[k]));
        }

        // ---- convert + LDS write (own slot; dbuf -> no WAR hazard) ----
        {
            short8 o;
#pragma unroll
            for (int i = 0; i < 8; i++) o[i] = f2bf(ga[i]);
            *(short8*)&Ap[grow * FPITCH + gcc * 8] = o;
        }

        // ---- prefetch next relation's first 4 indices (resolve during barrier+MFMA) ----
        if (r + 1 < NREL) {
            int nrs = rp_s[(r + 1) * (GM + 1) + grow];
            int nre = rp_s[(r + 1) * (GM + 1) + grow + 1];
            if (nrs < nre) {
                pf0 = bsrc[nrs];
                pf1 = bsrc[nrs + 1];
                pf2 = bsrc[nrs + 2];
                pf3 = bsrc[nrs + 3];
            }
        }
        __syncthreads();

        // ---- MFMA phase: A from LDS (M=16), B already in registers ----
#pragma unroll
        for (int ks = 0; ks < 4; ks++) {
            short8 af = *(const short8*)&Ap[lm * FPITCH + ks * 32 + lq * 8];
            __builtin_amdgcn_s_setprio(1);
            acc[0] = __builtin_amdgcn_mfma_f32_16x16x32_bf16(af, bfr[0][ks], acc[0], 0, 0, 0);
            acc[1] = __builtin_amdgcn_mfma_f32_16x16x32_bf16(af, bfr[1][ks], acc[1], 0, 0, 0);
            __builtin_amdgcn_s_setprio(0);
        }
        // no trailing barrier: next relation writes the OTHER buffer
    }

    __syncthreads();   // last MFMA read As[0] (r=8); safe to reuse as Et after this

    // ---- epilogue: counts-weighted bias, activation, store ----
    if (!last) {
        short (*Et)[FPITCH] = (short(*)[FPITCH])&As[0][0];
#pragma unroll
        for (int reg = 0; reg < 4; reg++) {
            int rl = lq * 4 + reg;
            float cr[NREL];
#pragma unroll
            for (int rr = 0; rr < NREL; rr++)
                cr[rr] = (float)(rp_s[rr * (GM + 1) + rl + 1] - rp_s[rr * (GM + 1) + rl]);
#pragma unroll
            for (int nt = 0; nt < 2; nt++) {
                int n = n0 + nt * 16 + lm;
                float b = 0.f;
#pragma unroll
                for (int rr = 0; rr < NREL; rr++) b += cr[rr] * bias_s[rr * HID + n];
                float o = fmaxf(acc[nt][reg] + b, 0.f);
                Et[rl][n] = f2bf(o);
            }
        }
        __syncthreads();
        {
            int row = tid >> 4, cc = tid & 15;
            int d = row0 + row;                  // always < NNODES (exact division)
            *(short8*)(HoutBf + (size_t)d * HID + cc * 8) = *(const short8*)&Et[row][cc * 8];
        }
    } else {
#pragma unroll
        for (int reg = 0; reg < 4; reg++) {
            int rl = lq * 4 + reg;
            int d  = row0 + rl;
            float cr[NREL];
#pragma unroll
            for (int rr = 0; rr < NREL; rr++)
                cr[rr] = (float)(rp_s[rr * (GM + 1) + rl + 1] - rp_s[rr * (GM + 1) + rl]);
#pragma unroll
            for (int nt = 0; nt < 2; nt++) {
                int n = n0 + nt * 16 + lm;
                float b = 0.f;
#pragma unroll
                for (int rr = 0; rr < NREL; rr++) b += cr[rr] * bias_s[rr * HID + n];
                HoutF[(size_t)d * HID + n] = acc[nt][reg] + b;
            }
        }
    }
}

// ---------------- driver ----------------

extern "C" void kernel_launch(void* const* d_in, const int* in_sizes, int n_in,
                              void* d_out, int out_size, void* d_ws, size_t ws_size,
                              hipStream_t stream) {
    const int*   edge_index = (const int*)d_in[0];   // [2, NEDGES]: row0=dest, row1=src
    const int*   etype      = (const int*)d_in[1];
    const float* emb        = (const float*)d_in[2];
    const float* W          = (const float*)d_in[3]; // [3,9,128,128]
    const float* Bias       = (const float*)d_in[4]; // [3,9,128]
    float*       out        = (float*)d_out;

    const int* dst  = edge_index;
    const int* srcA = edge_index + NEDGES;

    // ws layout (no S; H double-buffered)
    short* Ebf  = (short*)d_ws;                             // 50000*128 bf16
    short* HbfA = Ebf  + (size_t)NNODES * HID;              // 50000*128 bf16
    short* HbfB = HbfA + (size_t)NNODES * HID;              // 50000*128 bf16
    short* Wt2  = HbfB + (size_t)NNODES * HID;              // 3*128*1152 bf16
    int*   bsrc     = (int*)(Wt2 + (size_t)NLAYERS * HID * KTOT);  // NEDGES + 8 pad
    int*   bins     = bsrc + NEDGES + 8;
    int*   cursor   = bins + NBINS;
    int*   rowptr   = cursor + NBINS;                       // NBINS+1
    int*   blocksum = rowptr + NBINS + 1;
    int*   blockoff = blocksum + NBLK;

    hipMemsetAsync(bins, 0, NBINS * sizeof(int), stream);
    prep_kernel<<<HIST_BLKS + EMB_BLKS + W_BLKS, 256, 0, stream>>>(
        dst, etype, bins, emb, Ebf, W, Wt2);
    scan_pass1<<<NBLK, 256, 0, stream>>>(bins, blocksum);
    scan_pass2<<<1, 512, 0, stream>>>(blocksum, blockoff, rowptr);
    scan_pass3<<<NBLK, 256, 0, stream>>>(bins, blockoff, rowptr, cursor);
    place_kernel<<<(NEDGES + 255) / 256, 256, 0, stream>>>(dst, srcA, etype, cursor, bsrc);

    const int nblocks = NNODES / GM;   // 3125 (exact)
    const short* Hin = Ebf;
    for (int l = 0; l < NLAYERS; l++) {
        int last = (l + 1 == NLAYERS);
        short* Hout = (l == 0) ? HbfA : HbfB;       // alternate; never in-place
        if (l == 2) Hout = HbfA;                    // unused on last layer
        const short* Wtl = Wt2 + (size_t)l * HID * KTOT;
        const float* Bl  = Bias + (size_t)l * NREL * HID;
        fused_kernel<<<nblocks, 256, 0, stream>>>(
            Hin, Wtl, Bl, rowptr, bsrc, Hout, out, last);
        Hin = Hout;
    }
}

// Round 10
// 558.831 us; speedup vs baseline: 2.3978x; 1.6284x over previous
//
#include <hip/hip_runtime.h>

#define NNODES 50000
#define HID 128
#define NREL 9
#define NLAYERS 3
#define NEDGES 600000

#define NBINS (NREL * NNODES)          // 450000, bin = r*NNODES + d  (r-major)
#define SCAN_CHUNK 1024
#define NBLK ((NBINS + SCAN_CHUNK - 1) / SCAN_CHUNK)   // 440

#define KTOT (NREL * HID)               // 1152
#define GM 16                           // fused M-tile -> 3125 blocks (50000/16 exact)
#define FPITCH 136                      // panel/Et pitch in shorts (272 B rows, 2-way banks = free)

// prep_kernel block ranges
#define HIST_BLKS ((NEDGES + 255) / 256)            // 2344
#define EMB_BLKS  ((NNODES * HID / 8) / 256)        // 3125
#define W_BLKS    (NLAYERS * NREL)                  // 27

typedef __attribute__((ext_vector_type(8))) short short8;
typedef __attribute__((ext_vector_type(4))) float f32x4;

__device__ __forceinline__ short f2bf(float f) {
    union { float f; unsigned u; } c; c.f = f;
    unsigned r = c.u + 0x7fff + ((c.u >> 16) & 1);   // RNE
    return (short)(r >> 16);
}
__device__ __forceinline__ float bf2f(short v) {
    return __uint_as_float(((unsigned)(unsigned short)v) << 16);
}

// ---------------- prep: histogram + emb convert + W convert (one dispatch) ----------------
// Wt2[l][n][r*128+kk] = bf16(W[l][r][kk][n])   (r-major K)

__global__ __launch_bounds__(256) void prep_kernel(const int* __restrict__ dst,
                                                   const int* __restrict__ etype,
                                                   int* __restrict__ bins,
                                                   const float* __restrict__ E,
                                                   short* __restrict__ Ebf,
                                                   const float* __restrict__ W,
                                                   short* __restrict__ Wt2) {
    int b = blockIdx.x, tid = threadIdx.x;
    if (b < HIST_BLKS) {
        int e = b * 256 + tid;
        if (e < NEDGES) {
            int bin = etype[e] * NNODES + dst[e];
            atomicAdd(&bins[bin], 1);
        }
    } else if (b < HIST_BLKS + EMB_BLKS) {
        int gid = (b - HIST_BLKS) * 256 + tid;
        const float* p = E + (size_t)gid * 8;
        float4 v0 = *(const float4*)p;
        float4 v1 = *(const float4*)(p + 4);
        short8 o = {f2bf(v0.x), f2bf(v0.y), f2bf(v0.z), f2bf(v0.w),
                    f2bf(v1.x), f2bf(v1.y), f2bf(v1.z), f2bf(v1.w)};
        *(short8*)(Ebf + (size_t)gid * 8) = o;
    } else {
        int lr = b - HIST_BLKS - EMB_BLKS;
        int l = lr / NREL, r = lr - l * NREL;
        const float* w = W + (size_t)lr * HID * HID;
        short* o = Wt2 + (size_t)l * HID * KTOT;
#pragma unroll 4
        for (int i = 0; i < 64; i++) {
            int elem = i * 256 + tid;
            int kk = elem >> 7, n = elem & 127;
            o[(size_t)n * KTOT + r * HID + kk] = f2bf(w[elem]);
        }
    }
}

// ---------------- scans ----------------

__global__ __launch_bounds__(256) void scan_pass1(const int* __restrict__ bins,
                                                  int* __restrict__ blocksum) {
    __shared__ int red[256];
    int b = blockIdx.x, t = threadIdx.x;
    int i0 = b * SCAN_CHUNK + t * 4;
    int s = 0;
#pragma unroll
    for (int k = 0; k < 4; k++)
        if (i0 + k < NBINS) s += bins[i0 + k];
    red[t] = s;
    __syncthreads();
    for (int off = 128; off > 0; off >>= 1) {
        if (t < off) red[t] += red[t + off];
        __syncthreads();
    }
    if (t == 0) blocksum[b] = red[0];
}

__global__ __launch_bounds__(512) void scan_pass2(const int* __restrict__ blocksum,
                                                  int* __restrict__ blockoff,
                                                  int* __restrict__ rowptr) {
    __shared__ int s[512];
    int t = threadIdx.x;
    int v = (t < NBLK) ? blocksum[t] : 0;
    s[t] = v;
    __syncthreads();
    for (int off = 1; off < 512; off <<= 1) {
        int x = (t >= off) ? s[t - off] : 0;
        __syncthreads();
        s[t] += x;
        __syncthreads();
    }
    if (t < NBLK) blockoff[t] = s[t] - v;
    if (t == 0) rowptr[NBINS] = NEDGES;
}

__global__ __launch_bounds__(256) void scan_pass3(const int* __restrict__ bins,
                                                  const int* __restrict__ blockoff,
                                                  int* __restrict__ rowptr,
                                                  int* __restrict__ cursor) {
    __shared__ int sc[256];
    int b = blockIdx.x, t = threadIdx.x;
    int i0 = b * SCAN_CHUNK + t * 4;
    int v[4], p[4];
    int s = 0;
#pragma unroll
    for (int k = 0; k < 4; k++) {
        v[k] = (i0 + k < NBINS) ? bins[i0 + k] : 0;
        p[k] = s;
        s += v[k];
    }
    sc[t] = s;
    __syncthreads();
    for (int off = 1; off < 256; off <<= 1) {
        int x = (t >= off) ? sc[t - off] : 0;
        __syncthreads();
        sc[t] += x;
        __syncthreads();
    }
    int base = blockoff[b] + (sc[t] - s);
#pragma unroll
    for (int k = 0; k < 4; k++) {
        if (i0 + k < NBINS) {
            rowptr[i0 + k] = base + p[k];
            cursor[i0 + k] = base + p[k];
        }
    }
}

__global__ void place_kernel(const int* __restrict__ dst, const int* __restrict__ src,
                             const int* __restrict__ etype,
                             int* __restrict__ cursor, int* __restrict__ bsrc) {
    int e = blockIdx.x * blockDim.x + threadIdx.x;
    if (e < 8) bsrc[NEDGES + e] = 0;     // zero the lookahead pad
    if (e < NEDGES) {
        int bin = etype[e] * NNODES + dst[e];
        int pos = atomicAdd(&cursor[bin], 1);
        bsrc[pos] = src[e];
    }
}

// ---------------- fused layer: gather (4-wide edge groups) + GEMM + bias + act ----------------
// Round-9 geometry (GM=16, 3125 blocks, 14.3 KB LDS) with the register cap RELAXED:
// launch_bounds(256,4) -> VGPR cap 128, compiler lands ~64-80, NO scratch spills
// (round 9's (256,8) forced VGPR=32 -> 617 MB spill writes -> 266 us/layer).
// Residency: VGPR-bound 4-8 blocks/CU vs round-5's ~2.5 -> more outstanding
// random H reads. All inner loops byte-identical to round 5 (passed).
// Wave shape 16Mx32N; C mapping (verified): row = lq*4+reg, col = n0+nt*16+lm.

__global__ __launch_bounds__(256, 4) void fused_kernel(const short* __restrict__ Hin,
                                                       const short* __restrict__ Wt2l,
                                                       const float* __restrict__ Bias, // [9][128]
                                                       const int* __restrict__ rowptr,
                                                       const int* __restrict__ bsrc,
                                                       short* __restrict__ HoutBf,     // !last
                                                       float* __restrict__ HoutF,      // last
                                                       int last) {
    __shared__ short As[2][GM * FPITCH];          // 2 x 4352 B, [0] reused as Et
    __shared__ int   rp_s[NREL * (GM + 1)];       // 153 ints
    __shared__ float bias_s[NREL * HID];          // 4608 B

    int tid  = threadIdx.x;
    int wave = tid >> 6, lane = tid & 63;
    int lm = lane & 15, lq = lane >> 4;
    int row0 = blockIdx.x * GM;
    int n0   = wave * 32;                 // wave's N base
    int grow = tid >> 4;                  // 0..15 dest row (16 lanes/row)
    int gcc  = tid & 15;                  // 8-col group (16 B/lane)

    // ---- prologue: prefetch rel-0 first 4 indices (pad-safe raw loads) ----
    int rs0 = rowptr[row0 + grow];
    int re0 = rowptr[row0 + grow + 1];
    int pf0 = 0, pf1 = 0, pf2 = 0, pf3 = 0;
    if (rs0 < re0) {
        pf0 = bsrc[rs0];
        pf1 = bsrc[rs0 + 1];
        pf2 = bsrc[rs0 + 2];
        pf3 = bsrc[rs0 + 3];
    }

    // stage rowptr spans (9 x 17; index r*NNODES + row0 + o always valid: o=16 at
    // r=8,row0=49984 -> NBINS, which rowptr holds)
    for (int i = tid; i < NREL * (GM + 1); i += 256) {
        int r = i / (GM + 1), o = i - r * (GM + 1);
        rp_s[i] = rowptr[r * NNODES + row0 + o];
    }
    for (int i = tid; i < NREL * HID; i += 256) bias_s[i] = Bias[i];

    f32x4 acc[2];
    acc[0] = (f32x4){0.f, 0.f, 0.f, 0.f};
    acc[1] = (f32x4){0.f, 0.f, 0.f, 0.f};

    __syncthreads();

    const short* wb = Wt2l + (size_t)(n0 + lm) * KTOT + lq * 8;
    const short* hb = Hin + gcc * 8;

    for (int r = 0; r < NREL; r++) {
        short* Ap = &As[r & 1][0];

        // ---- B prefetch: 8 independent 16B loads, consumed after the barrier ----
        short8 bfr[2][4];
#pragma unroll
        for (int nt = 0; nt < 2; nt++)
#pragma unroll
            for (int ks = 0; ks < 4; ks++)
                bfr[nt][ks] = *(const short8*)(wb + (size_t)nt * 16 * KTOT + r * HID + ks * 32);

        // ---- gather: 4-wide edge groups, register accumulation ----
        int rs = rp_s[r * (GM + 1) + grow];
        int re = rp_s[r * (GM + 1) + grow + 1];
        float ga[8];
#pragma unroll
        for (int i = 0; i < 8; i++) ga[i] = 0.f;

        int j = rs;
        if (j < re) {
            // first group: indices already prefetched
            int rem = re - j;
            int s0 = pf0;
            int s1 = (rem > 1) ? pf1 : s0;
            int s2 = (rem > 2) ? pf2 : s0;
            int s3 = (rem > 3) ? pf3 : s0;
            short8 a = *(const short8*)(hb + (size_t)s0 * HID);
            short8 b = *(const short8*)(hb + (size_t)s1 * HID);
            short8 c = *(const short8*)(hb + (size_t)s2 * HID);
            short8 d = *(const short8*)(hb + (size_t)s3 * HID);
            float m1 = (rem > 1) ? 1.f : 0.f;
            float m2 = (rem > 2) ? 1.f : 0.f;
            float m3 = (rem > 3) ? 1.f : 0.f;
#pragma unroll
            for (int k = 0; k < 8; k++)
                ga[k] += (bf2f(a[k]) + m1 * bf2f(b[k])) + (m2 * bf2f(c[k]) + m3 * bf2f(d[k]));
            j += 4;
        }
        for (; j < re; j += 4) {
            // rare long-bin path (>4 edges): pad-safe idx loads, clamped values
            int rem = re - j;
            int s0 = bsrc[j];
            int t1 = bsrc[j + 1];
            int t2 = bsrc[j + 2];
            int t3 = bsrc[j + 3];
            int s1 = (rem > 1) ? t1 : s0;
            int s2 = (rem > 2) ? t2 : s0;
            int s3 = (rem > 3) ? t3 : s0;
            short8 a = *(const short8*)(hb + (size_t)s0 * HID);
            short8 b = *(const short8*)(hb + (size_t)s1 * HID);
            short8 c = *(const short8*)(hb + (size_t)s2 * HID);
            short8 d = *(const short8*)(hb + (size_t)s3 * HID);
            float m1 = (rem > 1) ? 1.f : 0.f;
            float m2 = (rem > 2) ? 1.f : 0.f;
            float m3 = (rem > 3) ? 1.f : 0.f;
#pragma unroll
            for (int k = 0; k < 8; k++)
                ga[k] += (bf2f(a[k]) + m1 * bf2f(b[k])) + (m2 * bf2f(c[k]) + m3 * bf2f(d[k]));
        }

        // ---- convert + LDS write (own slot; dbuf -> no WAR hazard) ----
        {
            short8 o;
#pragma unroll
            for (int i = 0; i < 8; i++) o[i] = f2bf(ga[i]);
            *(short8*)&Ap[grow * FPITCH + gcc * 8] = o;
        }

        // ---- prefetch next relation's first 4 indices (resolve during barrier+MFMA) ----
        if (r + 1 < NREL) {
            int nrs = rp_s[(r + 1) * (GM + 1) + grow];
            int nre = rp_s[(r + 1) * (GM + 1) + grow + 1];
            if (nrs < nre) {
                pf0 = bsrc[nrs];
                pf1 = bsrc[nrs + 1];
                pf2 = bsrc[nrs + 2];
                pf3 = bsrc[nrs + 3];
            }
        }
        __syncthreads();

        // ---- MFMA phase: A from LDS (M=16), B already in registers ----
#pragma unroll
        for (int ks = 0; ks < 4; ks++) {
            short8 af = *(const short8*)&Ap[lm * FPITCH + ks * 32 + lq * 8];
            __builtin_amdgcn_s_setprio(1);
            acc[0] = __builtin_amdgcn_mfma_f32_16x16x32_bf16(af, bfr[0][ks], acc[0], 0, 0, 0);
            acc[1] = __builtin_amdgcn_mfma_f32_16x16x32_bf16(af, bfr[1][ks], acc[1], 0, 0, 0);
            __builtin_amdgcn_s_setprio(0);
        }
        // no trailing barrier: next relation writes the OTHER buffer
    }

    __syncthreads();   // last MFMA read As[0] (r=8); safe to reuse as Et after this

    // ---- epilogue: counts-weighted bias, activation, store ----
    if (!last) {
        short (*Et)[FPITCH] = (short(*)[FPITCH])&As[0][0];
#pragma unroll
        for (int reg = 0; reg < 4; reg++) {
            int rl = lq * 4 + reg;
            float cr[NREL];
#pragma unroll
            for (int rr = 0; rr < NREL; rr++)
                cr[rr] = (float)(rp_s[rr * (GM + 1) + rl + 1] - rp_s[rr * (GM + 1) + rl]);
#pragma unroll
            for (int nt = 0; nt < 2; nt++) {
                int n = n0 + nt * 16 + lm;
                float b = 0.f;
#pragma unroll
                for (int rr = 0; rr < NREL; rr++) b += cr[rr] * bias_s[rr * HID + n];
                float o = fmaxf(acc[nt][reg] + b, 0.f);
                Et[rl][n] = f2bf(o);
            }
        }
        __syncthreads();
        {
            int row = tid >> 4, cc = tid & 15;
            int d = row0 + row;                  // always < NNODES (exact division)
            *(short8*)(HoutBf + (size_t)d * HID + cc * 8) = *(const short8*)&Et[row][cc * 8];
        }
    } else {
#pragma unroll
        for (int reg = 0; reg < 4; reg++) {
            int rl = lq * 4 + reg;
            int d  = row0 + rl;
            float cr[NREL];
#pragma unroll
            for (int rr = 0; rr < NREL; rr++)
                cr[rr] = (float)(rp_s[rr * (GM + 1) + rl + 1] - rp_s[rr * (GM + 1) + rl]);
#pragma unroll
            for (int nt = 0; nt < 2; nt++) {
                int n = n0 + nt * 16 + lm;
                float b = 0.f;
#pragma unroll
                for (int rr = 0; rr < NREL; rr++) b += cr[rr] * bias_s[rr * HID + n];
                HoutF[(size_t)d * HID + n] = acc[nt][reg] + b;
            }
        }
    }
}

// ---------------- driver ----------------

extern "C" void kernel_launch(void* const* d_in, const int* in_sizes, int n_in,
                              void* d_out, int out_size, void* d_ws, size_t ws_size,
                              hipStream_t stream) {
    const int*   edge_index = (const int*)d_in[0];   // [2, NEDGES]: row0=dest, row1=src
    const int*   etype      = (const int*)d_in[1];
    const float* emb        = (const float*)d_in[2];
    const float* W          = (const float*)d_in[3]; // [3,9,128,128]
    const float* Bias       = (const float*)d_in[4]; // [3,9,128]
    float*       out        = (float*)d_out;

    const int* dst  = edge_index;
    const int* srcA = edge_index + NEDGES;

    // ws layout (no S; H double-buffered)
    short* Ebf  = (short*)d_ws;                             // 50000*128 bf16
    short* HbfA = Ebf  + (size_t)NNODES * HID;              // 50000*128 bf16
    short* HbfB = HbfA + (size_t)NNODES * HID;              // 50000*128 bf16
    short* Wt2  = HbfB + (size_t)NNODES * HID;              // 3*128*1152 bf16
    int*   bsrc     = (int*)(Wt2 + (size_t)NLAYERS * HID * KTOT);  // NEDGES + 8 pad
    int*   bins     = bsrc + NEDGES + 8;
    int*   cursor   = bins + NBINS;
    int*   rowptr   = cursor + NBINS;                       // NBINS+1
    int*   blocksum = rowptr + NBINS + 1;
    int*   blockoff = blocksum + NBLK;

    hipMemsetAsync(bins, 0, NBINS * sizeof(int), stream);
    prep_kernel<<<HIST_BLKS + EMB_BLKS + W_BLKS, 256, 0, stream>>>(
        dst, etype, bins, emb, Ebf, W, Wt2);
    scan_pass1<<<NBLK, 256, 0, stream>>>(bins, blocksum);
    scan_pass2<<<1, 512, 0, stream>>>(blocksum, blockoff, rowptr);
    scan_pass3<<<NBLK, 256, 0, stream>>>(bins, blockoff, rowptr, cursor);
    place_kernel<<<(NEDGES + 255) / 256, 256, 0, stream>>>(dst, srcA, etype, cursor, bsrc);

    const int nblocks = NNODES / GM;   // 3125 (exact)
    const short* Hin = Ebf;
    for (int l = 0; l < NLAYERS; l++) {
        int last = (l + 1 == NLAYERS);
        short* Hout = (l == 0) ? HbfA : HbfB;       // alternate; never in-place
        if (l == 2) Hout = HbfA;                    // unused on last layer
        const short* Wtl = Wt2 + (size_t)l * HID * KTOT;
        const float* Bl  = Bias + (size_t)l * NREL * HID;
        fused_kernel<<<nblocks, 256, 0, stream>>>(
            Hin, Wtl, Bl, rowptr, bsrc, Hout, out, last);
        Hin = Hout;
    }
}

// Round 11
// 417.285 us; speedup vs baseline: 3.2112x; 1.3392x over previous
//
#include <hip/hip_runtime.h>

#define NNODES 50000
#define HID 128
#define NREL 9
#define NLAYERS 3
#define NEDGES 600000

#define NBINS (NREL * NNODES)          // 450000, bin = d*9+r
#define SCAN_CHUNK 1024
#define NBLK ((NBINS + SCAN_CHUNK - 1) / SCAN_CHUNK)   // 440

#define KTOT (NREL * HID)               // 1152
#define GM2 64                          // GEMM M-tile
#define BK 64                           // K-chunk
#define NCHUNK (KTOT / BK)              // 18
#define PITCH 72                        // LDS pitch (shorts): 144 B rows -> 2-way banks (free)
#define EPITCH 136                      // epilogue LDS pitch

// prep_kernel block ranges
#define HIST_BLKS ((NEDGES + 255) / 256)            // 2344
#define EMB_BLKS  ((NNODES * HID / 8) / 256)        // 3125
#define W_BLKS    (NLAYERS * NREL)                  // 27

typedef __attribute__((ext_vector_type(8))) short short8;
typedef __attribute__((ext_vector_type(4))) float f32x4;

__device__ __forceinline__ short f2bf(float f) {
    union { float f; unsigned u; } c; c.f = f;
    unsigned r = c.u + 0x7fff + ((c.u >> 16) & 1);   // RNE
    return (short)(r >> 16);
}
__device__ __forceinline__ float bf2f(short v) {
    return __uint_as_float(((unsigned)(unsigned short)v) << 16);
}

// ---------------- prep: histogram + emb convert + W convert (one dispatch) ----------------
// Wt2[l][n][r*128+kk] = bf16(W[l][r][kk][n])

__global__ __launch_bounds__(256) void prep_kernel(const int* __restrict__ dst,
                                                   const int* __restrict__ etype,
                                                   int* __restrict__ bins,
                                                   const float* __restrict__ E,
                                                   short* __restrict__ Ebf,
                                                   const float* __restrict__ W,
                                                   short* __restrict__ Wt2) {
    int b = blockIdx.x, tid = threadIdx.x;
    if (b < HIST_BLKS) {
        int e = b * 256 + tid;
        if (e < NEDGES) {
            int bin = dst[e] * NREL + etype[e];
            atomicAdd(&bins[bin], 1);
        }
    } else if (b < HIST_BLKS + EMB_BLKS) {
        int gid = (b - HIST_BLKS) * 256 + tid;
        const float* p = E + (size_t)gid * 8;
        float4 v0 = *(const float4*)p;
        float4 v1 = *(const float4*)(p + 4);
        short8 o = {f2bf(v0.x), f2bf(v0.y), f2bf(v0.z), f2bf(v0.w),
                    f2bf(v1.x), f2bf(v1.y), f2bf(v1.z), f2bf(v1.w)};
        *(short8*)(Ebf + (size_t)gid * 8) = o;
    } else {
        int lr = b - HIST_BLKS - EMB_BLKS;
        int l = lr / NREL, r = lr - l * NREL;
        const float* w = W + (size_t)lr * HID * HID;
        short* o = Wt2 + (size_t)l * HID * KTOT;
#pragma unroll 4
        for (int i = 0; i < 64; i++) {
            int elem = i * 256 + tid;
            int kk = elem >> 7, n = elem & 127;
            o[(size_t)n * KTOT + r * HID + kk] = f2bf(w[elem]);
        }
    }
}

// ---------------- scans (round-0 verbatim) ----------------

__global__ __launch_bounds__(256) void scan_pass1(const int* __restrict__ bins,
                                                  int* __restrict__ blocksum) {
    __shared__ int red[256];
    int b = blockIdx.x, t = threadIdx.x;
    int i0 = b * SCAN_CHUNK + t * 4;
    int s = 0;
#pragma unroll
    for (int k = 0; k < 4; k++)
        if (i0 + k < NBINS) s += bins[i0 + k];
    red[t] = s;
    __syncthreads();
    for (int off = 128; off > 0; off >>= 1) {
        if (t < off) red[t] += red[t + off];
        __syncthreads();
    }
    if (t == 0) blocksum[b] = red[0];
}

__global__ __launch_bounds__(512) void scan_pass2(const int* __restrict__ blocksum,
                                                  int* __restrict__ blockoff,
                                                  int* __restrict__ rowptr) {
    __shared__ int s[512];
    int t = threadIdx.x;
    int v = (t < NBLK) ? blocksum[t] : 0;
    s[t] = v;
    __syncthreads();
    for (int off = 1; off < 512; off <<= 1) {
        int x = (t >= off) ? s[t - off] : 0;
        __syncthreads();
        s[t] += x;
        __syncthreads();
    }
    if (t < NBLK) blockoff[t] = s[t] - v;
    if (t == 0) rowptr[NBINS] = NEDGES;
}

__global__ __launch_bounds__(256) void scan_pass3(const int* __restrict__ bins,
                                                  const int* __restrict__ blockoff,
                                                  int* __restrict__ rowptr,
                                                  int* __restrict__ cursor) {
    __shared__ int sc[256];
    int b = blockIdx.x, t = threadIdx.x;
    int i0 = b * SCAN_CHUNK + t * 4;
    int v[4], p[4];
    int s = 0;
#pragma unroll
    for (int k = 0; k < 4; k++) {
        v[k] = (i0 + k < NBINS) ? bins[i0 + k] : 0;
        p[k] = s;
        s += v[k];
    }
    sc[t] = s;
    __syncthreads();
    for (int off = 1; off < 256; off <<= 1) {
        int x = (t >= off) ? sc[t - off] : 0;
        __syncthreads();
        sc[t] += x;
        __syncthreads();
    }
    int base = blockoff[b] + (sc[t] - s);
#pragma unroll
    for (int k = 0; k < 4; k++) {
        if (i0 + k < NBINS) {
            rowptr[i0 + k] = base + p[k];
            cursor[i0 + k] = base + p[k];
        }
    }
}

__global__ void place_kernel(const int* __restrict__ dst, const int* __restrict__ src,
                             const int* __restrict__ etype,
                             int* __restrict__ cursor, int* __restrict__ bsrc) {
    int e = blockIdx.x * blockDim.x + threadIdx.x;
    if (e < NEDGES) {
        int bin = dst[e] * NREL + etype[e];
        int pos = atomicAdd(&cursor[bin], 1);
        bsrc[pos] = src[e];
    }
}

// ---------------- gather (round-0 verbatim): S[bin][0..127] = sum_{e in CSR(bin)} Hbf[src_e] ----------------

__global__ __launch_bounds__(256) void gather_kernel(const short* __restrict__ Hbf,
                                                     const int* __restrict__ bsrc,
                                                     const int* __restrict__ rowptr,
                                                     short* __restrict__ S) {
    int gid = blockIdx.x * blockDim.x + threadIdx.x;
    int bin = gid >> 3;
    if (bin >= NBINS) return;
    int ck  = gid & 7;            // 16 cols each
    int rs = rowptr[bin];
    int re = rowptr[bin + 1];
    float a[16];
#pragma unroll
    for (int i = 0; i < 16; i++) a[i] = 0.f;
    for (int j = rs; j < re; j++) {
        int s = bsrc[j];
        const short* hp = Hbf + (size_t)s * HID + ck * 16;
        short8 v0 = *(const short8*)hp;
        short8 v1 = *(const short8*)(hp + 8);
#pragma unroll
        for (int i = 0; i < 8; i++) a[i]     += bf2f(v0[i]);
#pragma unroll
        for (int i = 0; i < 8; i++) a[i + 8] += bf2f(v1[i]);
    }
    short8 o0 = {f2bf(a[0]),  f2bf(a[1]),  f2bf(a[2]),  f2bf(a[3]),
                 f2bf(a[4]),  f2bf(a[5]),  f2bf(a[6]),  f2bf(a[7])};
    short8 o1 = {f2bf(a[8]),  f2bf(a[9]),  f2bf(a[10]), f2bf(a[11]),
                 f2bf(a[12]), f2bf(a[13]), f2bf(a[14]), f2bf(a[15])};
    short* sp = S + (size_t)bin * HID + ck * 16;
    *(short8*)sp       = o0;
    *(short8*)(sp + 8) = o1;
}

// ---------------- gemm: round-0 structure + 2-deep S prefetch (even/odd slots) ----------------
// Per chunk the round-0 pipeline exposed ~half an L3 latency (S loads issued one
// MFMA-phase before consumption). Even/odd double-chunk body with two NAMED A
// staging slots (static indexing) issues A(k+2) right after chunk k's barrier ->
// window = 2 full chunks > L3 latency. B (Wt2, L2-hot) keeps the 1-deep window.

__global__ __launch_bounds__(256) void gemm_kernel(const short* __restrict__ S,
                                                   const short* __restrict__ Wt2l,
                                                   const float* __restrict__ Bias, // [9][128]
                                                   const int* __restrict__ rowptr,
                                                   short* __restrict__ HoutBf,     // !last: bf16+relu
                                                   float* __restrict__ HoutF,      // last: fp32
                                                   int last) {
    __shared__ short lds[GM2 * PITCH + HID * PITCH];   // As | Bs; reused as Et[64][EPITCH]
    __shared__ int   rp_s[GM2 * NREL + 1];
    __shared__ float bias_s[NREL * HID];
    short* As = lds;
    short* Bs = lds + GM2 * PITCH;

    int tid  = threadIdx.x;
    int wave = tid >> 6, lane = tid & 63;
    int row0 = blockIdx.x * GM2;
    int m0   = wave * 16;
    int lm = lane & 15, lq = lane >> 4;

    int rpbase = row0 * NREL;
    for (int i = tid; i <= GM2 * NREL; i += 256) {
        int g = rpbase + i;
        rp_s[i] = rowptr[(g < NBINS) ? g : NBINS];
    }
    for (int i = tid; i < NREL * HID; i += 256) bias_s[i] = Bias[i];

    // per-thread staging slots: 2 A rows + 4 B rows, fixed (row, ck)
    int rowL = tid >> 3;          // 0..31
    int ck   = tid & 7;           // col chunk (8 shorts)
    int ar0 = row0 + rowL;        if (ar0 > NNODES - 1) ar0 = NNODES - 1;
    int ar1 = row0 + 32 + rowL;   if (ar1 > NNODES - 1) ar1 = NNODES - 1;
    const short* pA0 = S + (size_t)ar0 * KTOT + ck * 8;
    const short* pA1 = S + (size_t)ar1 * KTOT + ck * 8;
    const short* pB0 = Wt2l + (size_t)(rowL      ) * KTOT + ck * 8;
    const short* pB1 = Wt2l + (size_t)(rowL + 32 ) * KTOT + ck * 8;
    const short* pB2 = Wt2l + (size_t)(rowL + 64 ) * KTOT + ck * 8;
    const short* pB3 = Wt2l + (size_t)(rowL + 96 ) * KTOT + ck * 8;

    // prologue: A slots for chunks 0 (E) and 1 (O); B for chunk 0
    short8 raE0 = *(const short8*)pA0;
    short8 raE1 = *(const short8*)pA1;
    short8 raO0 = *(const short8*)(pA0 + BK);
    short8 raO1 = *(const short8*)(pA1 + BK);
    short8 rb0 = *(const short8*)pB0;
    short8 rb1 = *(const short8*)pB1;
    short8 rb2 = *(const short8*)pB2;
    short8 rb3 = *(const short8*)pB3;

    f32x4 acc[8];
#pragma unroll
    for (int nt = 0; nt < 8; nt++) acc[nt] = (f32x4){0.f, 0.f, 0.f, 0.f};

    for (int kp = 0; kp < NCHUNK / 2; kp++) {
        int ke = 2 * kp;
        // ======== even chunk ke: consume slot E ========
        __syncthreads();          // prev chunk's fragment reads done
        *(short8*)&As[ rowL       * PITCH + ck * 8] = raE0;
        *(short8*)&As[(rowL + 32) * PITCH + ck * 8] = raE1;
        *(short8*)&Bs[ rowL       * PITCH + ck * 8] = rb0;
        *(short8*)&Bs[(rowL + 32) * PITCH + ck * 8] = rb1;
        *(short8*)&Bs[(rowL + 64) * PITCH + ck * 8] = rb2;
        *(short8*)&Bs[(rowL + 96) * PITCH + ck * 8] = rb3;
        __syncthreads();
        if (ke + 2 < NCHUNK) {    // refill slot E for chunk ke+2 (2-deep window)
            int off = (ke + 2) * BK;
            raE0 = *(const short8*)(pA0 + off);
            raE1 = *(const short8*)(pA1 + off);
        }
        {                         // B for odd chunk ke+1 (1-deep, L2-hot)
            int off = (ke + 1) * BK;
            rb0 = *(const short8*)(pB0 + off);
            rb1 = *(const short8*)(pB1 + off);
            rb2 = *(const short8*)(pB2 + off);
            rb3 = *(const short8*)(pB3 + off);
        }
#pragma unroll
        for (int ks = 0; ks < 2; ks++) {
            short8 af = *(const short8*)&As[(m0 + lm) * PITCH + ks * 32 + lq * 8];
#pragma unroll
            for (int nt = 0; nt < 8; nt++) {
                short8 bf = *(const short8*)&Bs[(nt * 16 + lm) * PITCH + ks * 32 + lq * 8];
                acc[nt] = __builtin_amdgcn_mfma_f32_16x16x32_bf16(af, bf, acc[nt], 0, 0, 0);
            }
        }
        // ======== odd chunk ke+1: consume slot O ========
        __syncthreads();
        *(short8*)&As[ rowL       * PITCH + ck * 8] = raO0;
        *(short8*)&As[(rowL + 32) * PITCH + ck * 8] = raO1;
        *(short8*)&Bs[ rowL       * PITCH + ck * 8] = rb0;
        *(short8*)&Bs[(rowL + 32) * PITCH + ck * 8] = rb1;
        *(short8*)&Bs[(rowL + 64) * PITCH + ck * 8] = rb2;
        *(short8*)&Bs[(rowL + 96) * PITCH + ck * 8] = rb3;
        __syncthreads();
        if (ke + 3 < NCHUNK) {    // refill slot O for chunk ke+3
            int off = (ke + 3) * BK;
            raO0 = *(const short8*)(pA0 + off);
            raO1 = *(const short8*)(pA1 + off);
        }
        if (ke + 2 < NCHUNK) {    // B for next even chunk
            int off = (ke + 2) * BK;
            rb0 = *(const short8*)(pB0 + off);
            rb1 = *(const short8*)(pB1 + off);
            rb2 = *(const short8*)(pB2 + off);
            rb3 = *(const short8*)(pB3 + off);
        }
#pragma unroll
        for (int ks = 0; ks < 2; ks++) {
            short8 af = *(const short8*)&As[(m0 + lm) * PITCH + ks * 32 + lq * 8];
#pragma unroll
            for (int nt = 0; nt < 8; nt++) {
                short8 bf = *(const short8*)&Bs[(nt * 16 + lm) * PITCH + ks * 32 + lq * 8];
                acc[nt] = __builtin_amdgcn_mfma_f32_16x16x32_bf16(af, bf, acc[nt], 0, 0, 0);
            }
        }
    }
    __syncthreads();   // As/Bs reads done; safe to reuse lds as Et

    // epilogue (round-0 verbatim). C/D layout: col = nt*16+lm, row(in tile) = m0 + lq*4 + reg
    if (!last) {
        short (*Et)[EPITCH] = (short(*)[EPITCH])lds;
#pragma unroll
        for (int reg = 0; reg < 4; reg++) {
            int rl = m0 + lq * 4 + reg;
            float cr[NREL];
#pragma unroll
            for (int r = 0; r < NREL; r++)
                cr[r] = (float)(rp_s[rl * NREL + r + 1] - rp_s[rl * NREL + r]);
#pragma unroll
            for (int nt = 0; nt < 8; nt++) {
                int n = nt * 16 + lm;
                float b = 0.f;
#pragma unroll
                for (int r = 0; r < NREL; r++) b += cr[r] * bias_s[r * HID + n];
                float o = fmaxf(acc[nt][reg] + b, 0.f);
                Et[rl][n] = f2bf(o);
            }
        }
        __syncthreads();
#pragma unroll
        for (int i = 0; i < 4; i++) {
            int p = i * 256 + tid;
            int row = p >> 4, cc = p & 15;
            int d = row0 + row;
            if (d < NNODES)
                *(short8*)(HoutBf + (size_t)d * HID + cc * 8) = *(const short8*)&Et[row][cc * 8];
        }
    } else {
#pragma unroll
        for (int reg = 0; reg < 4; reg++) {
            int rl = m0 + lq * 4 + reg;
            int d  = row0 + rl;
            if (d >= NNODES) continue;
            float cr[NREL];
#pragma unroll
            for (int r = 0; r < NREL; r++)
                cr[r] = (float)(rp_s[rl * NREL + r + 1] - rp_s[rl * NREL + r]);
#pragma unroll
            for (int nt = 0; nt < 8; nt++) {
                int n = nt * 16 + lm;
                float b = 0.f;
#pragma unroll
                for (int r = 0; r < NREL; r++) b += cr[r] * bias_s[r * HID + n];
                HoutF[(size_t)d * HID + n] = acc[nt][reg] + b;
            }
        }
    }
}

// ---------------- driver ----------------

extern "C" void kernel_launch(void* const* d_in, const int* in_sizes, int n_in,
                              void* d_out, int out_size, void* d_ws, size_t ws_size,
                              hipStream_t stream) {
    const int*   edge_index = (const int*)d_in[0];   // [2, NEDGES]: row0=dest, row1=src
    const int*   etype      = (const int*)d_in[1];
    const float* emb        = (const float*)d_in[2];
    const float* W          = (const float*)d_in[3]; // [3,9,128,128]
    const float* Bias       = (const float*)d_in[4]; // [3,9,128]
    float*       out        = (float*)d_out;

    const int* dst  = edge_index;
    const int* srcA = edge_index + NEDGES;

    // ws layout (round-0 verbatim)
    short* Ebf = (short*)d_ws;                              // 50000*128 bf16
    short* Hbf = Ebf + (size_t)NNODES * HID;                // 50000*128 bf16
    short* S   = Hbf + (size_t)NNODES * HID;                // 50000*1152 bf16 (115.2 MB)
    short* Wt2 = S + (size_t)NNODES * KTOT;                 // 3*128*1152 bf16
    int*   bsrc     = (int*)(Wt2 + (size_t)NLAYERS * HID * KTOT);
    int*   bins     = bsrc + NEDGES;
    int*   cursor   = bins + NBINS;
    int*   rowptr   = cursor + NBINS;                       // NBINS+1
    int*   blocksum = rowptr + NBINS + 1;
    int*   blockoff = blocksum + NBLK;

    hipMemsetAsync(bins, 0, NBINS * sizeof(int), stream);
    prep_kernel<<<HIST_BLKS + EMB_BLKS + W_BLKS, 256, 0, stream>>>(
        dst, etype, bins, emb, Ebf, W, Wt2);
    scan_pass1<<<NBLK, 256, 0, stream>>>(bins, blocksum);
    scan_pass2<<<1, 512, 0, stream>>>(blocksum, blockoff, rowptr);
    scan_pass3<<<NBLK, 256, 0, stream>>>(bins, blockoff, rowptr, cursor);
    place_kernel<<<(NEDGES + 255) / 256, 256, 0, stream>>>(dst, srcA, etype, cursor, bsrc);

    const short* Hin = Ebf;
    for (int l = 0; l < NLAYERS; l++) {
        gather_kernel<<<(NBINS * 8 + 255) / 256, 256, 0, stream>>>(Hin, bsrc, rowptr, S);
        const short* Wtl = Wt2 + (size_t)l * HID * KTOT;
        const float* Bl  = Bias + (size_t)l * NREL * HID;
        int last = (l + 1 == NLAYERS);
        gemm_kernel<<<(NNODES + GM2 - 1) / GM2, 256, 0, stream>>>(
            S, Wtl, Bl, rowptr, Hbf, out, last);
        Hin = Hbf;
    }
}